// Round 12
// baseline (269.232 us; speedup 1.0000x reference)
//
#include <hip/hip_runtime.h>
#include <hip/hip_bf16.h>

// ---------------------------------------------------------------------------
// ResidualSAGEBlock: block-private bucket sort -> CSR(+offs) -> fused
// (fp8 gather-mean -> LDS A-tile -> MFMA dual GEMM + BN stats) -> finalize.
// N=100000, D=128, E=1600000.
// R2: CSR gather replaced float-atomic scatter: 3095->812us.
// R7: 3-pass block-private counting sort: 757->409us.
// R8: bf16 gather source; offs folded into csrbuild; packed pairs: 409->306us.
// R10-R12: bf16 h/residual; 9 dispatches; replicated stats: 290us.
// R13 FAILED: fusion at 128-row blocks (3128 waves, occ 19%): 316us.
// R14 NEUTRAL: pk-f32 accumulate, buckets 128, prep merged: 291.9us.
// R15/R16 FAILED: XCD-affinity attempts (no placement control): 333/546us.
// R17 FAILED: spin-flag merged scan: 300.3us.
// R18: SBLK 512 (2 blk/CU sort side), generalized scan: 289.6us.
// R19: fp8(e4m3) gather source: FETCH 177->80MB, absmax unchanged 0.0625.
// R20: 8 nodes/wave gather (4x fewer chain payments): 275.6us.
// R21: mfma wave tile 32->16 rows (1563 blocks, 24 waves/CU): 257.1us.
// R22 NEUTRAL: fusion retry at 64-row blocks: 258.3us. FETCH 122->93MB won,
//      but gather waves halved (12512->6252) at same 4-in-flight/lane ->
//      gather phase 2x standalone time, ate the traffic win.
// R23: restore MLP inside fusion: edge loop unrolled to 8 loads in flight
//      per node (8x uint4 + 8x acc16 per trip; clamped 4-wide tail).
//      Per-wave outstanding bytes 2x -> aggregate MLP back to R20 level
//      WITH the fusion's traffic savings.
//      (Round 11 bench was an infra failure - resubmitted unchanged.)
// ---------------------------------------------------------------------------

#define D128 128
#define BSH2 7          // log2(nodes per bucket)
#define BSZ2 128        // nodes per bucket
#define MAXBUK 1024     // LDS bound for buckets (NBUK=782 actual)
#define SBLK 512        // sort blocks (2 per CU)
#define CAP  2816       // csrbuild LDS capacity (mean 2046, +17 sigma)
#define SREP 32         // stat replicas

typedef short bf16x8 __attribute__((ext_vector_type(8)));
typedef float f32x4  __attribute__((ext_vector_type(4)));
typedef float f32x2  __attribute__((ext_vector_type(2)));

static __device__ __forceinline__ unsigned short f2bf(float f) {
    unsigned u = __builtin_bit_cast(unsigned, f);
    unsigned r = u + 0x7fffu + ((u >> 16) & 1u);   // round-to-nearest-even
    return (unsigned short)(r >> 16);
}
static __device__ __forceinline__ float bflo(unsigned u) {   // low bf16 -> f32
    return __builtin_bit_cast(float, u << 16);
}
static __device__ __forceinline__ float bfhi(unsigned u) {   // high bf16 -> f32
    return __builtin_bit_cast(float, u & 0xffff0000u);
}

// accumulate 16 fp8 (one uint4) into 8 f32x2 accumulators via HW converts
static __device__ __forceinline__ void acc16(f32x2* a, uint4 w) {
    f32x2 t;
    t = __builtin_amdgcn_cvt_pk_f32_fp8((int)w.x, false); a[0] += t;
    t = __builtin_amdgcn_cvt_pk_f32_fp8((int)w.x, true);  a[1] += t;
    t = __builtin_amdgcn_cvt_pk_f32_fp8((int)w.y, false); a[2] += t;
    t = __builtin_amdgcn_cvt_pk_f32_fp8((int)w.y, true);  a[3] += t;
    t = __builtin_amdgcn_cvt_pk_f32_fp8((int)w.z, false); a[4] += t;
    t = __builtin_amdgcn_cvt_pk_f32_fp8((int)w.z, true);  a[5] += t;
    t = __builtin_amdgcn_cvt_pk_f32_fp8((int)w.w, false); a[6] += t;
    t = __builtin_amdgcn_cvt_pk_f32_fp8((int)w.w, true);  a[7] += t;
}

// --- sort pass 1: per-block bucket histogram + fused x->bf16/fp8 convert ---
// Blocks 0..15 additionally build swizzled bf16 B for MFMA and zero the
// replicated stats (former prep_kernel):
//   Bsw[t][c][lane][j] = Wcat[t*32 + (lane>>4)*8 + j][c*16 + (lane&15)]
//   Wcat[k][d] = k<128 ? Wl[d][k] : Wr[d][k-128].
__global__ __launch_bounds__(256) void bhist_kernel(
    const int* __restrict__ dst, int* __restrict__ ghist,
    const float* __restrict__ x, unsigned short* __restrict__ xb,
    unsigned char* __restrict__ xq,
    const float* __restrict__ Wl, const float* __restrict__ Wr,
    unsigned short* __restrict__ Bsw, float* __restrict__ stats,
    int E, int chunk, int NBUK, int total4) {
    __shared__ int lh[MAXBUK];
    int tid = threadIdx.x;
    int b   = blockIdx.x;
    if (b < 16) {                       // merged prep work
        int idx = b * 256 + tid;        // 0..4095
        stats[idx] = 0.f;               // 2 x 4096 = SREP*256 floats
        stats[idx + 4096] = 0.f;
        int l = idx & 63;
        int c = (idx >> 6) & 7;
        int t = idx >> 9;
        int d = c * 16 + (l & 15);
        int kbase = t * 32 + (l >> 4) * 8;
        unsigned short o[8];
#pragma unroll
        for (int j = 0; j < 8; ++j) {
            int k = kbase + j;
            float v = (k < 128) ? Wl[d * 128 + k] : Wr[d * 128 + (k - 128)];
            o[j] = f2bf(v);
        }
        *(uint4*)(Bsw + (size_t)idx * 8) = *(const uint4*)o;
    }
    for (int i = tid; i < NBUK; i += 256) lh[i] = 0;
    __syncthreads();
    int beg = b * chunk;
    int end = min(beg + chunk, E);
    for (int i = beg + tid; i < end; i += 256)
        atomicAdd(&lh[dst[i] >> BSH2], 1);
    __syncthreads();
    for (int i = tid; i < NBUK; i += 256) ghist[i * SBLK + b] = lh[i];
    // fused streaming conversion x (fp32) -> xb (bf16) + xq (fp8 e4m3)
    for (int i = b * 256 + tid; i < total4; i += 256 * SBLK) {
        float4 v = ((const float4*)x)[i];
        uint2 o;
        o.x = (unsigned)f2bf(v.x) | ((unsigned)f2bf(v.y) << 16);
        o.y = (unsigned)f2bf(v.z) | ((unsigned)f2bf(v.w) << 16);
        ((uint2*)xb)[i] = o;
        int q = __builtin_amdgcn_cvt_pk_fp8_f32(v.x, v.y, 0, false);
        q     = __builtin_amdgcn_cvt_pk_fp8_f32(v.z, v.w, q, true);
        ((unsigned*)xq)[i] = (unsigned)q;
    }
}

// --- scan stage 1: per-block (1024 elems) partial sums ---------------------
__global__ __launch_bounds__(256) void partial_kernel(const int* __restrict__ deg,
                                                      int* __restrict__ bsum, int N) {
    int tid  = threadIdx.x;
    int base = blockIdx.x * 1024 + tid * 4;
    int s = 0;
    if (base + 3 < N) {
        int4 v = *(const int4*)(deg + base);
        s = v.x + v.y + v.z + v.w;
    } else {
        for (int i = base; i < N; ++i) s += deg[i];
    }
    __shared__ int red[256];
    red[tid] = s;
    __syncthreads();
    for (int off = 128; off > 0; off >>= 1) {
        if (tid < off) red[tid] += red[tid + off];
        __syncthreads();
    }
    if (tid == 0) bsum[blockIdx.x] = red[0];
}

// --- scan stage 2 (final): per-block scan; bsum scan via 4-per-thread ------
// Supports NB2 <= 1024: thread t serial-sums bsum[4t..4t+3], LDS-scans the
// 256 sums, then every thread reconstructs this block's exclusive base.
__global__ __launch_bounds__(256) void scan_final_kernel(
    const int* __restrict__ deg, const int* __restrict__ bsum,
    int* __restrict__ offs, int M, int NB2) {
    __shared__ int sb[2][256];
    int tid = threadIdx.x;
    int b   = blockIdx.x;

    int i0 = 4 * tid;
    int p0 = (i0     < NB2) ? bsum[i0]     : 0;
    int p1 = (i0 + 1 < NB2) ? bsum[i0 + 1] : 0;
    int p2 = (i0 + 2 < NB2) ? bsum[i0 + 2] : 0;
    int p3 = (i0 + 3 < NB2) ? bsum[i0 + 3] : 0;
    int ps = p0 + p1 + p2 + p3;
    sb[0][tid] = ps;
    __syncthreads();
    int bpi = 0;
    for (int off = 1; off < 256; off <<= 1) {
        int u = sb[bpi][tid];
        if (tid >= off) u += sb[bpi][tid - off];
        sb[bpi ^ 1][tid] = u;
        __syncthreads();
        bpi ^= 1;
    }
    int excl = sb[bpi][tid] - ps;         // exclusive over 4-groups
    __syncthreads();
    sb[0][tid] = excl;
    __syncthreads();
    int q = b >> 2, r = b & 3;
    int ebsum = sb[0][q];
    if (r > 0) ebsum += bsum[4 * q];
    if (r > 1) ebsum += bsum[4 * q + 1];
    if (r > 2) ebsum += bsum[4 * q + 2];
    __syncthreads();

    int base = b * 1024 + tid * 4;
    int d0 = 0, d1 = 0, d2 = 0, d3 = 0;
    if (base + 3 < M) {
        int4 v = *(const int4*)(deg + base);
        d0 = v.x; d1 = v.y; d2 = v.z; d3 = v.w;
    } else {
        if (base     < M) d0 = deg[base];
        if (base + 1 < M) d1 = deg[base + 1];
        if (base + 2 < M) d2 = deg[base + 2];
        if (base + 3 < M) d3 = deg[base + 3];
    }
    int s = d0 + d1 + d2 + d3;
    sb[0][tid] = s;
    __syncthreads();
    int pi = 0;
    for (int off = 1; off < 256; off <<= 1) {
        int u = sb[pi][tid];
        if (tid >= off) u += sb[pi][tid - off];
        sb[pi ^ 1][tid] = u;
        __syncthreads();
        pi ^= 1;
    }
    int pre = sb[pi][tid] - s + ebsum;
    if (base + 3 < M) {
        int4 o = make_int4(pre, pre + d0, pre + d0 + d1, pre + d0 + d1 + d2);
        *(int4*)(offs + base) = o;
    } else {
        int p = pre;
        if (base     < M) { offs[base]     = p; p += d0; }
        if (base + 1 < M) { offs[base + 1] = p; p += d1; }
        if (base + 2 < M) { offs[base + 2] = p; }
    }
}

// --- sort pass 2: scatter packed (src<<8 | dst&255) into private ranges ----
__global__ __launch_bounds__(256) void bscatter_kernel(
    const int* __restrict__ src, const int* __restrict__ dst,
    const int* __restrict__ gsc, unsigned* __restrict__ pairs,
    int E, int chunk, int NBUK) {
    __shared__ int lcur[MAXBUK];
    int tid = threadIdx.x;
    int b   = blockIdx.x;
    for (int i = tid; i < NBUK; i += 256) lcur[i] = gsc[i * SBLK + b];
    __syncthreads();
    int beg = b * chunk;
    int end = min(beg + chunk, E);
    for (int i = beg + tid; i < end; i += 256) {
        int d = dst[i];
        int s = src[i];
        int pos = atomicAdd(&lcur[d >> BSH2], 1);
        pairs[pos] = ((unsigned)s << 8) | (unsigned)(d & 255);
    }
}

// --- per-bucket: local node histogram + scan -> offs; LDS sort -> csr ------
// BSZ2=128: counters 128..255 stay zero; 256-wide scan still yields correct
// exclusive prefixes, and pre[128] == len covers the offs[bucket_end] write.
__global__ __launch_bounds__(256) void csrbuild_kernel(
    const unsigned* __restrict__ pairs, const int* __restrict__ gsc,
    int* __restrict__ csr, int* __restrict__ offs, int N, int NBUK, int E) {
    __shared__ int lcnt[256];
    __shared__ int sbuf[2][256];
    __shared__ int lcsr[CAP];
    int b   = blockIdx.x;
    int tid = threadIdx.x;
    int nlo = b << BSH2;
    int base = gsc[(size_t)b * SBLK];                       // bucket start
    int end  = (b + 1 < NBUK) ? gsc[(size_t)(b + 1) * SBLK] : E;
    int len  = end - base;
    lcnt[tid] = 0;
    __syncthreads();
    for (int i = tid; i < len; i += 256)
        atomicAdd(&lcnt[pairs[base + i] & 127u], 1);
    __syncthreads();
    int c = lcnt[tid];
    sbuf[0][tid] = c;
    __syncthreads();
    int pi = 0;
    for (int off = 1; off < 256; off <<= 1) {
        int u = sbuf[pi][tid];
        if (tid >= off) u += sbuf[pi][tid - off];
        sbuf[pi ^ 1][tid] = u;
        __syncthreads();
        pi ^= 1;
    }
    int pre = sbuf[pi][tid] - c;
    if (tid <= BSZ2 && nlo + tid <= N) offs[nlo + tid] = base + pre;
    lcnt[tid] = pre;                                        // reuse as cursor
    __syncthreads();
    if (len <= CAP) {
        for (int i = tid; i < len; i += 256) {
            unsigned p = pairs[base + i];
            int pos = atomicAdd(&lcnt[p & 127u], 1);
            lcsr[pos] = (int)(p >> 8);
        }
        __syncthreads();
        for (int i = tid; i < len; i += 256) csr[base + i] = lcsr[i];
    } else {
        for (int i = tid; i < len; i += 256) {
            unsigned p = pairs[base + i];
            int pos = atomicAdd(&lcnt[p & 127u], 1);
            csr[base + pos] = (int)(p >> 8);
        }
    }
}

// --- fused: fp8 gather-mean -> swizzled LDS A-tile -> MFMA dual GEMM -------
// Block = 64 rows, wave = 16 rows. Phase 1: 2 passes x 8 nodes/wave (8
// lanes/node, lane owns one 16B chunk of the 128B fp8 row = 16 outputs);
// R23: edge loop unrolled to 8 loads in flight (2x MLP vs R22).
// Results written bf16 to atile with chunk_phys = chunk_log ^ (row&15).
// Phase 2: K=256 MFMA; ksteps 0-3 read atile, 4-7 read global xb.
// No b_l (cancelled by BN). aggb round trip eliminated.
__global__ __launch_bounds__(256) void gmfma_kernel(
    const int* __restrict__ offs, const int* __restrict__ csr,
    const unsigned char* __restrict__ xq,
    const unsigned short* __restrict__ xb,
    const unsigned short* __restrict__ Bsw,
    unsigned short* __restrict__ h16, float* __restrict__ stats, int N) {
    __shared__ unsigned short atile[4][16][128];   // 16 KB, swizzled
    __shared__ float red[4][256];
    int tid  = threadIdx.x;
    int w    = tid >> 6;
    int lane = tid & 63;
    int rowBase = blockIdx.x * 64 + w * 16;

    // ---- phase 1: gather-mean 16 rows per wave into swizzled LDS --------
    {
        int sub = (lane >> 3) & 7;     // node within pass
        int fl  = lane & 7;            // 16B chunk of the fp8 row
#pragma unroll
        for (int pass = 0; pass < 2; ++pass) {
            int r = pass * 8 + sub;            // local row 0..15
            int n = rowBase + r;
            f32x2 a[8];
#pragma unroll
            for (int j = 0; j < 8; ++j) {
                f32x2 z = {0.f, 0.f};
                a[j] = z;
            }
            float inv = 0.f;
            if (n < N) {
                int beg = offs[n], end = offs[n + 1];
                int deg = end - beg;
                int last = end - 1;
                int k = beg;
                for (; k + 8 <= end; k += 8) {         // 8 loads in flight
                    int s0 = csr[k];
                    int s1 = csr[k + 1];
                    int s2 = csr[k + 2];
                    int s3 = csr[k + 3];
                    int s4 = csr[k + 4];
                    int s5 = csr[k + 5];
                    int s6 = csr[k + 6];
                    int s7 = csr[k + 7];
                    uint4 w0 = *(const uint4*)(xq + (size_t)s0 * D128 + fl * 16);
                    uint4 w1 = *(const uint4*)(xq + (size_t)s1 * D128 + fl * 16);
                    uint4 w2 = *(const uint4*)(xq + (size_t)s2 * D128 + fl * 16);
                    uint4 w3 = *(const uint4*)(xq + (size_t)s3 * D128 + fl * 16);
                    uint4 w4 = *(const uint4*)(xq + (size_t)s4 * D128 + fl * 16);
                    uint4 w5 = *(const uint4*)(xq + (size_t)s5 * D128 + fl * 16);
                    uint4 w6 = *(const uint4*)(xq + (size_t)s6 * D128 + fl * 16);
                    uint4 w7 = *(const uint4*)(xq + (size_t)s7 * D128 + fl * 16);
                    acc16(a, w0);
                    acc16(a, w1);
                    acc16(a, w2);
                    acc16(a, w3);
                    acc16(a, w4);
                    acc16(a, w5);
                    acc16(a, w6);
                    acc16(a, w7);
                }
                for (; k < end; k += 4) {              // clamped 4-wide tail
                    int s0 = csr[k];
                    int s1 = csr[min(k + 1, last)];
                    int s2 = csr[min(k + 2, last)];
                    int s3 = csr[min(k + 3, last)];
                    uint4 w0 = *(const uint4*)(xq + (size_t)s0 * D128 + fl * 16);
                    uint4 w1 = *(const uint4*)(xq + (size_t)s1 * D128 + fl * 16);
                    uint4 w2 = *(const uint4*)(xq + (size_t)s2 * D128 + fl * 16);
                    uint4 w3 = *(const uint4*)(xq + (size_t)s3 * D128 + fl * 16);
                    acc16(a, w0);
                    if (k + 1 < end) acc16(a, w1);
                    if (k + 2 < end) acc16(a, w2);
                    if (k + 3 < end) acc16(a, w3);
                }
                if (deg > 0) inv = 1.0f / (float)deg;
            }
            // lane's 16 bf16 = logical chunks 2fl, 2fl+1; phys = c ^ (r&15)
            uint4 o1, o2;
            o1.x = (unsigned)f2bf(a[0].x * inv) | ((unsigned)f2bf(a[0].y * inv) << 16);
            o1.y = (unsigned)f2bf(a[1].x * inv) | ((unsigned)f2bf(a[1].y * inv) << 16);
            o1.z = (unsigned)f2bf(a[2].x * inv) | ((unsigned)f2bf(a[2].y * inv) << 16);
            o1.w = (unsigned)f2bf(a[3].x * inv) | ((unsigned)f2bf(a[3].y * inv) << 16);
            o2.x = (unsigned)f2bf(a[4].x * inv) | ((unsigned)f2bf(a[4].y * inv) << 16);
            o2.y = (unsigned)f2bf(a[5].x * inv) | ((unsigned)f2bf(a[5].y * inv) << 16);
            o2.z = (unsigned)f2bf(a[6].x * inv) | ((unsigned)f2bf(a[6].y * inv) << 16);
            o2.w = (unsigned)f2bf(a[7].x * inv) | ((unsigned)f2bf(a[7].y * inv) << 16);
            int c1 = (2 * fl)     ^ r;
            int c2 = (2 * fl + 1) ^ r;
            *(uint4*)(&atile[w][r][c1 * 8]) = o1;
            *(uint4*)(&atile[w][r][c2 * 8]) = o2;
        }
    }
    __syncthreads();

    // ---- phase 2: MFMA dual GEMM --------------------------------------
    int lc = lane & 15;    // tile col / A row
    int lq = lane >> 4;    // quarter
    f32x4 acc[8];
#pragma unroll
    for (int c = 0; c < 8; ++c) {
        f32x4 z = {0.f, 0.f, 0.f, 0.f};
        acc[c] = z;
    }
    int r0c = min(rowBase + lc, N - 1);
    for (int t = 0; t < 8; ++t) {
        bf16x8 a0;
        if (t < 4) {
            int cp = (t * 4 + lq) ^ lc;        // swizzled chunk
            a0 = *(const bf16x8*)(&atile[w][lc][cp * 8]);
        } else {
            a0 = *(const bf16x8*)(xb + (size_t)r0c * D128 + (t - 4) * 32 + lq * 8);
        }
#pragma unroll
        for (int c = 0; c < 8; ++c) {
            bf16x8 bf = *(const bf16x8*)(Bsw + ((size_t)((t * 8 + c) * 64 + lane)) * 8);
            acc[c] = __builtin_amdgcn_mfma_f32_16x16x32_bf16(a0, bf, acc[c], 0, 0, 0);
        }
    }
    float s[8], ss[8];
#pragma unroll
    for (int c = 0; c < 8; ++c) { s[c] = 0.f; ss[c] = 0.f; }
#pragma unroll
    for (int reg = 0; reg < 4; ++reg) {
        int row = rowBase + lq * 4 + reg;                 // C-layout row
        if (row < N) {
#pragma unroll
            for (int c = 0; c < 8; ++c) {
                float v = acc[c][reg];
                h16[(size_t)row * D128 + c * 16 + lc] = f2bf(v);
                s[c]  += v;
                ss[c] += v * v;
            }
        }
    }
#pragma unroll
    for (int c = 0; c < 8; ++c) {
        s[c]  += __shfl_xor(s[c], 16, 64);
        s[c]  += __shfl_xor(s[c], 32, 64);
        ss[c] += __shfl_xor(ss[c], 16, 64);
        ss[c] += __shfl_xor(ss[c], 32, 64);
    }
    if (lq == 0) {
#pragma unroll
        for (int c = 0; c < 8; ++c) {
            red[w][c * 16 + lc]       = s[c];
            red[w][128 + c * 16 + lc] = ss[c];
        }
    }
    __syncthreads();
    float tot = red[0][tid] + red[1][tid] + red[2][tid] + red[3][tid];
    atomicAdd(&stats[(blockIdx.x & (SREP - 1)) * 256 + tid], tot);
}

// --- finalize: sum stat replicas, BN params in LDS, out = relu(...) --------
__global__ __launch_bounds__(256) void finalize_kernel(
    const unsigned short* __restrict__ h16, const unsigned short* __restrict__ xb,
    const float* __restrict__ stats, const float* __restrict__ gamma,
    const float* __restrict__ beta, float* __restrict__ out,
    long long total4, float invN) {
    __shared__ float sscl[D128];
    __shared__ float sshf[D128];
    int tid = threadIdx.x;
    if (tid < D128) {
        float sum = 0.f, sq = 0.f;
#pragma unroll
        for (int r = 0; r < SREP; ++r) {
            sum += stats[r * 256 + tid];
            sq  += stats[r * 256 + 128 + tid];
        }
        float mean = sum * invN;
        float var  = sq * invN - mean * mean;
        float istd = rsqrtf(var + 1e-5f);
        float sc   = gamma[tid] * istd;
        sscl[tid] = sc;
        sshf[tid] = beta[tid] - mean * sc;
    }
    __syncthreads();
    long long i = (long long)blockIdx.x * 256 + tid;
    if (i >= total4) return;
    int d = (int)((i * 4) & 127);
    uint2 hv = ((const uint2*)h16)[i];
    uint2 xv = ((const uint2*)xb)[i];
    float4 o;
    o.x = fmaxf(fmaf(bflo(hv.x), sscl[d],     sshf[d])     + bflo(xv.x), 0.f);
    o.y = fmaxf(fmaf(bfhi(hv.x), sscl[d + 1], sshf[d + 1]) + bfhi(xv.x), 0.f);
    o.z = fmaxf(fmaf(bflo(hv.y), sscl[d + 2], sshf[d + 2]) + bflo(xv.y), 0.f);
    o.w = fmaxf(fmaf(bfhi(hv.y), sscl[d + 3], sshf[d + 3]) + bfhi(xv.y), 0.f);
    ((float4*)out)[i] = o;
}

extern "C" void kernel_launch(void* const* d_in, const int* in_sizes, int n_in,
                              void* d_out, int out_size, void* d_ws, size_t ws_size,
                              hipStream_t stream) {
    const float* x     = (const float*)d_in[0];
    const int*   eidx  = (const int*)d_in[1];
    const float* W_l   = (const float*)d_in[2];
    const float* W_r   = (const float*)d_in[4];
    const float* gamma = (const float*)d_in[5];
    const float* beta  = (const float*)d_in[6];

    const int D = in_sizes[3];            // 128
    const int N = in_sizes[0] / D;        // 100000
    const int E = in_sizes[1] / 2;        // 1600000

    const int* src = eidx;
    const int* dst = eidx + E;

    const int NBLK2 = (N + 63) / 64;          // fused gmfma blocks (1563)
    const int NBUK  = (N + BSZ2 - 1) / BSZ2;  // buckets (782)
    const int M     = NBUK * SBLK;            // ghist cells (400384)
    const int NB2   = (M + 1023) / 1024;      // scan blocks (391, <=1024)
    const int chunk = (E + SBLK - 1) / SBLK;  // edges per sort block (3125)
    const int total4 = N * D128 / 4;          // float4s in x

    // workspace layout (byte cursor, 64B-aligned chunks)
    char* wp = (char*)d_ws;
    auto alloc = [&](size_t bytes) {
        char* p = wp;
        wp += (bytes + 63) & ~(size_t)63;
        return p;
    };
    float*    stats = (float*)   alloc((size_t)SREP * 256 * 4);
    int*      offs  = (int*)     alloc((size_t)(N + 1) * 4);
    int*      csr   = (int*)     alloc((size_t)E * 4);
    unsigned* pairs = (unsigned*)alloc((size_t)E * 4);
    int*      ghist = (int*)     alloc((size_t)M * 4);
    int*      gsc   = (int*)     alloc((size_t)(M + 1) * 4);
    int*      bsum  = (int*)     alloc(1024 * 4);
    unsigned short* Bsw  = (unsigned short*)alloc(4096 * 16);
    unsigned short* xb   = (unsigned short*)alloc((size_t)N * D128 * 2);
    unsigned char*  xq   = (unsigned char*) alloc((size_t)N * D128);
    unsigned short* h16  = (unsigned short*)alloc((size_t)N * D128 * 2);

    float* outp = (float*)d_out;
    float invN = 1.0f / (float)N;

    // bucket hist (+ fused x->bf16/fp8 + prep) -> scan -> scatter
    bhist_kernel<<<SBLK, 256, 0, stream>>>(dst, ghist, x, xb, xq, W_l, W_r, Bsw,
                                           stats, E, chunk, NBUK, total4);
    partial_kernel<<<NB2, 256, 0, stream>>>(ghist, bsum, M);
    scan_final_kernel<<<NB2, 256, 0, stream>>>(ghist, bsum, gsc, M, NB2);
    bscatter_kernel<<<SBLK, 256, 0, stream>>>(src, dst, gsc, pairs, E, chunk, NBUK);

    // per-bucket CSR build (also writes offs)
    csrbuild_kernel<<<NBUK, 256, 0, stream>>>(pairs, gsc, csr, offs, N, NBUK, E);

    // fused gather + dual GEMM + BN stats (64-row blocks, 8-deep MLP)
    gmfma_kernel<<<NBLK2, 256, 0, stream>>>(offs, csr, xq, xb, Bsw, h16, stats, N);

    {
        long long t4 = (long long)N * D128 / 4;
        finalize_kernel<<<(int)((t4 + 255) / 256), 256, 0, stream>>>(
            h16, xb, stats, gamma, beta, outp, t4, invN);
    }
}

// Round 13
// 256.697 us; speedup vs baseline: 1.0488x; 1.0488x over previous
//
#include <hip/hip_runtime.h>
#include <hip/hip_bf16.h>

// ---------------------------------------------------------------------------
// ResidualSAGEBlock: block-private bucket sort -> CSR(+offs) -> fp8 gather ->
// MFMA bf16 dual GEMM (+in-kernel BN stats) -> finalize(BN+res+ReLU).
// N=100000, D=128, E=1600000.
// R2: CSR gather replaced float-atomic scatter: 3095->812us.
// R7: 3-pass block-private counting sort: 757->409us.
// R8: bf16 gather source; offs folded into csrbuild; packed pairs: 409->306us.
// R10-R12: bf16 h/residual; 9 dispatches; replicated stats: 290us.
// R13 FAILED: fusion at 128-row blocks (3128 waves, occ 19%): 316us.
// R14 NEUTRAL: pk-f32 accumulate, buckets 128, prep merged: 291.9us.
// R15/R16 FAILED: XCD-affinity attempts (no placement control): 333/546us.
// R17 FAILED: spin-flag merged scan: 300.3us.
// R18: SBLK 512 (2 blk/CU sort side), generalized scan: 289.6us.
// R19: fp8(e4m3) gather source: FETCH 177->80MB, absmax unchanged 0.0625.
// R20: 8 nodes/wave gather (4x fewer chain payments): 275.6us.
// R21: mfma wave tile 32->16 rows (1563 blocks, 24 waves/CU): 257.1us. BEST.
// R22 NEUTRAL: fusion retry at 64-row blocks: 258.3us (gather waves halved).
// R23 FAILED: 8-deep unroll in fused gather: VGPR 48->96 crossed the 64-VGPR
//      occupancy step (occ 33->18%, rate 1.84->1.39TB/s): 269us.
//      Fusion triangle (VGPR/occupancy/MLP) closed - 3 variants all lose.
// R24: REVERT to R21 (best verified). All dispatches within ~1.5-2x of
//      their BW/latency floors; falsified levers: fusion (x3), XCD
//      affinity (x2), deeper unroll (x1), spin-scan (x1).
// ---------------------------------------------------------------------------

#define D128 128
#define BSH2 7          // log2(nodes per bucket)
#define BSZ2 128        // nodes per bucket
#define MAXBUK 1024     // LDS bound for buckets (NBUK=782 actual)
#define SBLK 512        // sort blocks (2 per CU)
#define CAP  2816       // csrbuild LDS capacity (mean 2046, +17 sigma)
#define SREP 32         // stat replicas

typedef short bf16x8 __attribute__((ext_vector_type(8)));
typedef float f32x4  __attribute__((ext_vector_type(4)));
typedef float f32x2  __attribute__((ext_vector_type(2)));

static __device__ __forceinline__ unsigned short f2bf(float f) {
    unsigned u = __builtin_bit_cast(unsigned, f);
    unsigned r = u + 0x7fffu + ((u >> 16) & 1u);   // round-to-nearest-even
    return (unsigned short)(r >> 16);
}
static __device__ __forceinline__ float bflo(unsigned u) {   // low bf16 -> f32
    return __builtin_bit_cast(float, u << 16);
}
static __device__ __forceinline__ float bfhi(unsigned u) {   // high bf16 -> f32
    return __builtin_bit_cast(float, u & 0xffff0000u);
}

// accumulate 16 fp8 (one uint4) into 8 f32x2 accumulators via HW converts
static __device__ __forceinline__ void acc16(f32x2* a, uint4 w) {
    f32x2 t;
    t = __builtin_amdgcn_cvt_pk_f32_fp8((int)w.x, false); a[0] += t;
    t = __builtin_amdgcn_cvt_pk_f32_fp8((int)w.x, true);  a[1] += t;
    t = __builtin_amdgcn_cvt_pk_f32_fp8((int)w.y, false); a[2] += t;
    t = __builtin_amdgcn_cvt_pk_f32_fp8((int)w.y, true);  a[3] += t;
    t = __builtin_amdgcn_cvt_pk_f32_fp8((int)w.z, false); a[4] += t;
    t = __builtin_amdgcn_cvt_pk_f32_fp8((int)w.z, true);  a[5] += t;
    t = __builtin_amdgcn_cvt_pk_f32_fp8((int)w.w, false); a[6] += t;
    t = __builtin_amdgcn_cvt_pk_f32_fp8((int)w.w, true);  a[7] += t;
}

// --- sort pass 1: per-block bucket histogram + fused x->bf16/fp8 convert ---
// Blocks 0..15 additionally build swizzled bf16 B for MFMA and zero the
// replicated stats (former prep_kernel):
//   Bsw[t][c][lane][j] = Wcat[t*32 + (lane>>4)*8 + j][c*16 + (lane&15)]
//   Wcat[k][d] = k<128 ? Wl[d][k] : Wr[d][k-128].
__global__ __launch_bounds__(256) void bhist_kernel(
    const int* __restrict__ dst, int* __restrict__ ghist,
    const float* __restrict__ x, unsigned short* __restrict__ xb,
    unsigned char* __restrict__ xq,
    const float* __restrict__ Wl, const float* __restrict__ Wr,
    unsigned short* __restrict__ Bsw, float* __restrict__ stats,
    int E, int chunk, int NBUK, int total4) {
    __shared__ int lh[MAXBUK];
    int tid = threadIdx.x;
    int b   = blockIdx.x;
    if (b < 16) {                       // merged prep work
        int idx = b * 256 + tid;        // 0..4095
        stats[idx] = 0.f;               // 2 x 4096 = SREP*256 floats
        stats[idx + 4096] = 0.f;
        int l = idx & 63;
        int c = (idx >> 6) & 7;
        int t = idx >> 9;
        int d = c * 16 + (l & 15);
        int kbase = t * 32 + (l >> 4) * 8;
        unsigned short o[8];
#pragma unroll
        for (int j = 0; j < 8; ++j) {
            int k = kbase + j;
            float v = (k < 128) ? Wl[d * 128 + k] : Wr[d * 128 + (k - 128)];
            o[j] = f2bf(v);
        }
        *(uint4*)(Bsw + (size_t)idx * 8) = *(const uint4*)o;
    }
    for (int i = tid; i < NBUK; i += 256) lh[i] = 0;
    __syncthreads();
    int beg = b * chunk;
    int end = min(beg + chunk, E);
    for (int i = beg + tid; i < end; i += 256)
        atomicAdd(&lh[dst[i] >> BSH2], 1);
    __syncthreads();
    for (int i = tid; i < NBUK; i += 256) ghist[i * SBLK + b] = lh[i];
    // fused streaming conversion x (fp32) -> xb (bf16) + xq (fp8 e4m3)
    for (int i = b * 256 + tid; i < total4; i += 256 * SBLK) {
        float4 v = ((const float4*)x)[i];
        uint2 o;
        o.x = (unsigned)f2bf(v.x) | ((unsigned)f2bf(v.y) << 16);
        o.y = (unsigned)f2bf(v.z) | ((unsigned)f2bf(v.w) << 16);
        ((uint2*)xb)[i] = o;
        int q = __builtin_amdgcn_cvt_pk_fp8_f32(v.x, v.y, 0, false);
        q     = __builtin_amdgcn_cvt_pk_fp8_f32(v.z, v.w, q, true);
        ((unsigned*)xq)[i] = (unsigned)q;
    }
}

// --- scan stage 1: per-block (1024 elems) partial sums ---------------------
__global__ __launch_bounds__(256) void partial_kernel(const int* __restrict__ deg,
                                                      int* __restrict__ bsum, int N) {
    int tid  = threadIdx.x;
    int base = blockIdx.x * 1024 + tid * 4;
    int s = 0;
    if (base + 3 < N) {
        int4 v = *(const int4*)(deg + base);
        s = v.x + v.y + v.z + v.w;
    } else {
        for (int i = base; i < N; ++i) s += deg[i];
    }
    __shared__ int red[256];
    red[tid] = s;
    __syncthreads();
    for (int off = 128; off > 0; off >>= 1) {
        if (tid < off) red[tid] += red[tid + off];
        __syncthreads();
    }
    if (tid == 0) bsum[blockIdx.x] = red[0];
}

// --- scan stage 2 (final): per-block scan; bsum scan via 4-per-thread ------
// Supports NB2 <= 1024: thread t serial-sums bsum[4t..4t+3], LDS-scans the
// 256 sums, then every thread reconstructs this block's exclusive base.
__global__ __launch_bounds__(256) void scan_final_kernel(
    const int* __restrict__ deg, const int* __restrict__ bsum,
    int* __restrict__ offs, int M, int NB2) {
    __shared__ int sb[2][256];
    int tid = threadIdx.x;
    int b   = blockIdx.x;

    int i0 = 4 * tid;
    int p0 = (i0     < NB2) ? bsum[i0]     : 0;
    int p1 = (i0 + 1 < NB2) ? bsum[i0 + 1] : 0;
    int p2 = (i0 + 2 < NB2) ? bsum[i0 + 2] : 0;
    int p3 = (i0 + 3 < NB2) ? bsum[i0 + 3] : 0;
    int ps = p0 + p1 + p2 + p3;
    sb[0][tid] = ps;
    __syncthreads();
    int bpi = 0;
    for (int off = 1; off < 256; off <<= 1) {
        int u = sb[bpi][tid];
        if (tid >= off) u += sb[bpi][tid - off];
        sb[bpi ^ 1][tid] = u;
        __syncthreads();
        bpi ^= 1;
    }
    int excl = sb[bpi][tid] - ps;         // exclusive over 4-groups
    __syncthreads();
    sb[0][tid] = excl;
    __syncthreads();
    int q = b >> 2, r = b & 3;
    int ebsum = sb[0][q];
    if (r > 0) ebsum += bsum[4 * q];
    if (r > 1) ebsum += bsum[4 * q + 1];
    if (r > 2) ebsum += bsum[4 * q + 2];
    __syncthreads();

    int base = b * 1024 + tid * 4;
    int d0 = 0, d1 = 0, d2 = 0, d3 = 0;
    if (base + 3 < M) {
        int4 v = *(const int4*)(deg + base);
        d0 = v.x; d1 = v.y; d2 = v.z; d3 = v.w;
    } else {
        if (base     < M) d0 = deg[base];
        if (base + 1 < M) d1 = deg[base + 1];
        if (base + 2 < M) d2 = deg[base + 2];
        if (base + 3 < M) d3 = deg[base + 3];
    }
    int s = d0 + d1 + d2 + d3;
    sb[0][tid] = s;
    __syncthreads();
    int pi = 0;
    for (int off = 1; off < 256; off <<= 1) {
        int u = sb[pi][tid];
        if (tid >= off) u += sb[pi][tid - off];
        sb[pi ^ 1][tid] = u;
        __syncthreads();
        pi ^= 1;
    }
    int pre = sb[pi][tid] - s + ebsum;
    if (base + 3 < M) {
        int4 o = make_int4(pre, pre + d0, pre + d0 + d1, pre + d0 + d1 + d2);
        *(int4*)(offs + base) = o;
    } else {
        int p = pre;
        if (base     < M) { offs[base]     = p; p += d0; }
        if (base + 1 < M) { offs[base + 1] = p; p += d1; }
        if (base + 2 < M) { offs[base + 2] = p; }
    }
}

// --- sort pass 2: scatter packed (src<<8 | dst&255) into private ranges ----
__global__ __launch_bounds__(256) void bscatter_kernel(
    const int* __restrict__ src, const int* __restrict__ dst,
    const int* __restrict__ gsc, unsigned* __restrict__ pairs,
    int E, int chunk, int NBUK) {
    __shared__ int lcur[MAXBUK];
    int tid = threadIdx.x;
    int b   = blockIdx.x;
    for (int i = tid; i < NBUK; i += 256) lcur[i] = gsc[i * SBLK + b];
    __syncthreads();
    int beg = b * chunk;
    int end = min(beg + chunk, E);
    for (int i = beg + tid; i < end; i += 256) {
        int d = dst[i];
        int s = src[i];
        int pos = atomicAdd(&lcur[d >> BSH2], 1);
        pairs[pos] = ((unsigned)s << 8) | (unsigned)(d & 255);
    }
}

// --- per-bucket: local node histogram + scan -> offs; LDS sort -> csr ------
// BSZ2=128: counters 128..255 stay zero; 256-wide scan still yields correct
// exclusive prefixes, and pre[128] == len covers the offs[bucket_end] write.
__global__ __launch_bounds__(256) void csrbuild_kernel(
    const unsigned* __restrict__ pairs, const int* __restrict__ gsc,
    int* __restrict__ csr, int* __restrict__ offs, int N, int NBUK, int E) {
    __shared__ int lcnt[256];
    __shared__ int sbuf[2][256];
    __shared__ int lcsr[CAP];
    int b   = blockIdx.x;
    int tid = threadIdx.x;
    int nlo = b << BSH2;
    int base = gsc[(size_t)b * SBLK];                       // bucket start
    int end  = (b + 1 < NBUK) ? gsc[(size_t)(b + 1) * SBLK] : E;
    int len  = end - base;
    lcnt[tid] = 0;
    __syncthreads();
    for (int i = tid; i < len; i += 256)
        atomicAdd(&lcnt[pairs[base + i] & 127u], 1);
    __syncthreads();
    int c = lcnt[tid];
    sbuf[0][tid] = c;
    __syncthreads();
    int pi = 0;
    for (int off = 1; off < 256; off <<= 1) {
        int u = sbuf[pi][tid];
        if (tid >= off) u += sbuf[pi][tid - off];
        sbuf[pi ^ 1][tid] = u;
        __syncthreads();
        pi ^= 1;
    }
    int pre = sbuf[pi][tid] - c;
    if (tid <= BSZ2 && nlo + tid <= N) offs[nlo + tid] = base + pre;
    lcnt[tid] = pre;                                        // reuse as cursor
    __syncthreads();
    if (len <= CAP) {
        for (int i = tid; i < len; i += 256) {
            unsigned p = pairs[base + i];
            int pos = atomicAdd(&lcnt[p & 127u], 1);
            lcsr[pos] = (int)(p >> 8);
        }
        __syncthreads();
        for (int i = tid; i < len; i += 256) csr[base + i] = lcsr[i];
    } else {
        for (int i = tid; i < len; i += 256) {
            unsigned p = pairs[base + i];
            int pos = atomicAdd(&lcnt[p & 127u], 1);
            csr[base + pos] = (int)(p >> 8);
        }
    }
}

// --- gather-mean from fp8 xq, 8 nodes per wave ------------------------------
// Lane l: node subgroup sub = (l>>3) (8 lanes each), chunk fl = l&7 (16B of
// the 128B fp8 row). Each lane owns its 16 output elements end-to-end: no
// cross-lane reduction. Loads clamped to end-1 (hot line), predicated acc.
__global__ __launch_bounds__(256) void gather_kernel(
    const int* __restrict__ offs, const int* __restrict__ csr,
    const unsigned char* __restrict__ xq, unsigned short* __restrict__ aggb,
    int N) {
    int tid  = threadIdx.x;
    int sub  = (tid >> 3) & 7;         // node subgroup within wave
    int fl   = tid & 7;                // 16B chunk
    int wave = blockIdx.x * 4 + (tid >> 6);
    int n    = wave * 8 + sub;

    f32x2 a[8];
#pragma unroll
    for (int j = 0; j < 8; ++j) {
        f32x2 z = {0.f, 0.f};
        a[j] = z;
    }
    float inv = 0.f;
    if (n < N) {
        int beg = offs[n], end = offs[n + 1];
        int deg = end - beg;
        int last = end - 1;
        for (int k = beg; k < end; k += 4) {
            int s0 = csr[k];
            int s1 = csr[min(k + 1, last)];
            int s2 = csr[min(k + 2, last)];
            int s3 = csr[min(k + 3, last)];
            uint4 w0 = *(const uint4*)(xq + (size_t)s0 * D128 + fl * 16);
            uint4 w1 = *(const uint4*)(xq + (size_t)s1 * D128 + fl * 16);
            uint4 w2 = *(const uint4*)(xq + (size_t)s2 * D128 + fl * 16);
            uint4 w3 = *(const uint4*)(xq + (size_t)s3 * D128 + fl * 16);
            acc16(a, w0);
            if (k + 1 < end) acc16(a, w1);
            if (k + 2 < end) acc16(a, w2);
            if (k + 3 < end) acc16(a, w3);
        }
        if (deg > 0) inv = 1.0f / (float)deg;
    }
    // write this lane's 16 bf16 (32B); padded rows (n in [N,Npad)) get zeros
    unsigned short* dp = aggb + (size_t)n * D128 + fl * 16;
    uint4 o1, o2;
    o1.x = (unsigned)f2bf(a[0].x * inv) | ((unsigned)f2bf(a[0].y * inv) << 16);
    o1.y = (unsigned)f2bf(a[1].x * inv) | ((unsigned)f2bf(a[1].y * inv) << 16);
    o1.z = (unsigned)f2bf(a[2].x * inv) | ((unsigned)f2bf(a[2].y * inv) << 16);
    o1.w = (unsigned)f2bf(a[3].x * inv) | ((unsigned)f2bf(a[3].y * inv) << 16);
    o2.x = (unsigned)f2bf(a[4].x * inv) | ((unsigned)f2bf(a[4].y * inv) << 16);
    o2.y = (unsigned)f2bf(a[5].x * inv) | ((unsigned)f2bf(a[5].y * inv) << 16);
    o2.z = (unsigned)f2bf(a[6].x * inv) | ((unsigned)f2bf(a[6].y * inv) << 16);
    o2.w = (unsigned)f2bf(a[7].x * inv) | ((unsigned)f2bf(a[7].y * inv) << 16);
    *(uint4*)dp       = o1;
    *(uint4*)(dp + 8) = o2;
}

// --- MFMA dual GEMM -> bf16 h + BN stats into replicated accumulators ------
// K=256: ksteps 0-3 read aggb, 4-7 read xb. No b_l (cancelled by BN).
// One 16-row group per wave (block = 64 rows): acc 8 x f32x4, grid
// 1563 blocks = 24.4 waves/CU offered -> 2x MLP for the latency-bound
// A/Bsw load streams.
__global__ __launch_bounds__(256) void mfma_kernel(
    const unsigned short* __restrict__ aggb, const unsigned short* __restrict__ xb,
    const unsigned short* __restrict__ Bsw,
    unsigned short* __restrict__ h16, float* __restrict__ stats, int N) {
    __shared__ float red[4][256];
    int tid  = threadIdx.x;
    int w    = tid >> 6;
    int lane = tid & 63;
    int lc   = lane & 15;    // tile col
    int lq   = lane >> 4;    // quarter
    int rowBase = blockIdx.x * 64 + w * 16;

    f32x4 acc[8];
#pragma unroll
    for (int c = 0; c < 8; ++c) {
        f32x4 z = {0.f, 0.f, 0.f, 0.f};
        acc[c] = z;
    }
    int r0  = rowBase + lc;
    int r0c = min(r0, N - 1);
    for (int t = 0; t < 8; ++t) {
        const unsigned short* p0;
        if (t < 4) {
            p0 = aggb + (size_t)r0 * D128 + t * 32 + lq * 8;
        } else {
            p0 = xb + (size_t)r0c * D128 + (t - 4) * 32 + lq * 8;
        }
        bf16x8 a0 = *(const bf16x8*)p0;
#pragma unroll
        for (int c = 0; c < 8; ++c) {
            bf16x8 bf = *(const bf16x8*)(Bsw + ((size_t)((t * 8 + c) * 64 + lane)) * 8);
            acc[c] = __builtin_amdgcn_mfma_f32_16x16x32_bf16(a0, bf, acc[c], 0, 0, 0);
        }
    }
    float s[8], ss[8];
#pragma unroll
    for (int c = 0; c < 8; ++c) { s[c] = 0.f; ss[c] = 0.f; }
#pragma unroll
    for (int reg = 0; reg < 4; ++reg) {
        int row = rowBase + lq * 4 + reg;                 // C-layout row
        if (row < N) {
#pragma unroll
            for (int c = 0; c < 8; ++c) {
                float v = acc[c][reg];
                h16[(size_t)row * D128 + c * 16 + lc] = f2bf(v);
                s[c]  += v;
                ss[c] += v * v;
            }
        }
    }
#pragma unroll
    for (int c = 0; c < 8; ++c) {
        s[c]  += __shfl_xor(s[c], 16, 64);
        s[c]  += __shfl_xor(s[c], 32, 64);
        ss[c] += __shfl_xor(ss[c], 16, 64);
        ss[c] += __shfl_xor(ss[c], 32, 64);
    }
    if (lq == 0) {
#pragma unroll
        for (int c = 0; c < 8; ++c) {
            red[w][c * 16 + lc]       = s[c];
            red[w][128 + c * 16 + lc] = ss[c];
        }
    }
    __syncthreads();
    float tot = red[0][tid] + red[1][tid] + red[2][tid] + red[3][tid];
    atomicAdd(&stats[(blockIdx.x & (SREP - 1)) * 256 + tid], tot);
}

// --- finalize: sum stat replicas, BN params in LDS, out = relu(...) --------
__global__ __launch_bounds__(256) void finalize_kernel(
    const unsigned short* __restrict__ h16, const unsigned short* __restrict__ xb,
    const float* __restrict__ stats, const float* __restrict__ gamma,
    const float* __restrict__ beta, float* __restrict__ out,
    long long total4, float invN) {
    __shared__ float sscl[D128];
    __shared__ float sshf[D128];
    int tid = threadIdx.x;
    if (tid < D128) {
        float sum = 0.f, sq = 0.f;
#pragma unroll
        for (int r = 0; r < SREP; ++r) {
            sum += stats[r * 256 + tid];
            sq  += stats[r * 256 + 128 + tid];
        }
        float mean = sum * invN;
        float var  = sq * invN - mean * mean;
        float istd = rsqrtf(var + 1e-5f);
        float sc   = gamma[tid] * istd;
        sscl[tid] = sc;
        sshf[tid] = beta[tid] - mean * sc;
    }
    __syncthreads();
    long long i = (long long)blockIdx.x * 256 + tid;
    if (i >= total4) return;
    int d = (int)((i * 4) & 127);
    uint2 hv = ((const uint2*)h16)[i];
    uint2 xv = ((const uint2*)xb)[i];
    float4 o;
    o.x = fmaxf(fmaf(bflo(hv.x), sscl[d],     sshf[d])     + bflo(xv.x), 0.f);
    o.y = fmaxf(fmaf(bfhi(hv.x), sscl[d + 1], sshf[d + 1]) + bfhi(xv.x), 0.f);
    o.z = fmaxf(fmaf(bflo(hv.y), sscl[d + 2], sshf[d + 2]) + bflo(xv.y), 0.f);
    o.w = fmaxf(fmaf(bfhi(hv.y), sscl[d + 3], sshf[d + 3]) + bfhi(xv.y), 0.f);
    ((float4*)out)[i] = o;
}

extern "C" void kernel_launch(void* const* d_in, const int* in_sizes, int n_in,
                              void* d_out, int out_size, void* d_ws, size_t ws_size,
                              hipStream_t stream) {
    const float* x     = (const float*)d_in[0];
    const int*   eidx  = (const int*)d_in[1];
    const float* W_l   = (const float*)d_in[2];
    const float* W_r   = (const float*)d_in[4];
    const float* gamma = (const float*)d_in[5];
    const float* beta  = (const float*)d_in[6];

    const int D = in_sizes[3];            // 128
    const int N = in_sizes[0] / D;        // 100000
    const int E = in_sizes[1] / 2;        // 1600000

    const int* src = eidx;
    const int* dst = eidx + E;

    const int NBLK  = (N + 127) / 128;        // 128-row groups (782)
    const int Npad  = NBLK * 128;             // padded rows (100096)
    const int NBLK2 = (N + 63) / 64;          // mfma blocks (1563)
    const int NBUK  = (N + BSZ2 - 1) / BSZ2;  // buckets (782)
    const int M     = NBUK * SBLK;            // ghist cells (400384)
    const int NB2   = (M + 1023) / 1024;      // scan blocks (391, <=1024)
    const int chunk = (E + SBLK - 1) / SBLK;  // edges per sort block (3125)
    const int total4 = N * D128 / 4;          // float4s in x

    // workspace layout (byte cursor, 64B-aligned chunks)
    char* wp = (char*)d_ws;
    auto alloc = [&](size_t bytes) {
        char* p = wp;
        wp += (bytes + 63) & ~(size_t)63;
        return p;
    };
    float*    stats = (float*)   alloc((size_t)SREP * 256 * 4);
    int*      offs  = (int*)     alloc((size_t)(N + 1) * 4);
    int*      csr   = (int*)     alloc((size_t)E * 4);
    unsigned* pairs = (unsigned*)alloc((size_t)E * 4);
    int*      ghist = (int*)     alloc((size_t)M * 4);
    int*      gsc   = (int*)     alloc((size_t)(M + 1) * 4);
    int*      bsum  = (int*)     alloc(1024 * 4);
    unsigned short* Bsw  = (unsigned short*)alloc(4096 * 16);
    unsigned short* xb   = (unsigned short*)alloc((size_t)N * D128 * 2);
    unsigned char*  xq   = (unsigned char*) alloc((size_t)N * D128);
    unsigned short* aggb = (unsigned short*)alloc((size_t)Npad * D128 * 2);
    unsigned short* h16  = (unsigned short*)alloc((size_t)N * D128 * 2);

    float* outp = (float*)d_out;
    float invN = 1.0f / (float)N;

    // bucket hist (+ fused x->bf16/fp8 + prep) -> scan -> scatter
    bhist_kernel<<<SBLK, 256, 0, stream>>>(dst, ghist, x, xb, xq, W_l, W_r, Bsw,
                                           stats, E, chunk, NBUK, total4);
    partial_kernel<<<NB2, 256, 0, stream>>>(ghist, bsum, M);
    scan_final_kernel<<<NB2, 256, 0, stream>>>(ghist, bsum, gsc, M, NB2);
    bscatter_kernel<<<SBLK, 256, 0, stream>>>(src, dst, gsc, pairs, E, chunk, NBUK);

    // per-bucket CSR build (also writes offs)
    csrbuild_kernel<<<NBUK, 256, 0, stream>>>(pairs, gsc, csr, offs, N, NBUK, E);

    // fp8-source gather: 8 nodes per wave, 32 nodes per block
    gather_kernel<<<Npad / 32, 256, 0, stream>>>(offs, csr, xq, aggb, N);

    // 64-row mfma blocks (1563): 2x offered waves vs 128-row blocks
    mfma_kernel<<<NBLK2, 256, 0, stream>>>(aggb, xb, Bsw, h16, stats, N);

    {
        long long t4 = (long long)N * D128 / 4;
        finalize_kernel<<<(int)((t4 + 255) / 256), 256, 0, stream>>>(
            h16, xb, stats, gamma, beta, outp, t4, invN);
    }
}